// Round 8
// baseline (365.273 us; speedup 1.0000x reference)
//
#include <hip/hip_runtime.h>

// ---------------------------------------------------------------------------
// TimeMoeAttention: X@Wq/Wk/Wv + bias -> continuous-time RoPE -> causal GQA
// attention -> @Wo.  B=2, S=2048, H=2048, NH=16, NKV=4, HD=128.
// I/O fp32; internal bf16 + fp32 MFMA accumulation.
// R8: (1) gemm1 rope epilogue uses prefetched bf16 cos|sin pair table (no
//     global loads inside barrier-bracketed passes); (2) attn waves own 32 q
//     rows (2 q-sets) -> each K/V LDS read feeds 2 MFMAs (issue-bound fix).
// ---------------------------------------------------------------------------

#define S_LEN 2048
#define BATCH 2
#define NH    16
#define NKV   4
#define HD    128

typedef float  f32x4  __attribute__((ext_vector_type(4)));
typedef __bf16 bf16x8 __attribute__((ext_vector_type(8)));
typedef unsigned int u32x4 __attribute__((ext_vector_type(4)));
typedef unsigned int u32x2 __attribute__((ext_vector_type(2)));

__device__ inline unsigned short f2bf(float f) {
    unsigned u = __builtin_bit_cast(unsigned, f);
    unsigned r = (u + 0x7fffu + ((u >> 16) & 1u)) >> 16;   // RNE
    return (unsigned short)r;
}

// async global->LDS, 16 bytes per lane
__device__ inline void gload_lds16(const void* g, void* l) {
    __builtin_amdgcn_global_load_lds(
        (const __attribute__((address_space(1))) unsigned int*)g,
        (__attribute__((address_space(3))) unsigned int*)l, 16, 0, 0);
}

// ---------------------------------------------------------------------------
// Fused transposes: wq|wk|wv (fp32) -> Wt (bf16, [3072][2048]).  z selects.
// ---------------------------------------------------------------------------
__global__ void transpose_qkv(const float* __restrict__ wq,
                              const float* __restrict__ wk,
                              const float* __restrict__ wv,
                              unsigned short* __restrict__ Wt) {
    int z = blockIdx.z;
    const float* src = (z == 0) ? wq : ((z == 1) ? wk : wv);
    int C = (z == 0) ? 2048 : 512;
    long doff = (z == 0) ? 0L : ((z == 1) ? 2048L * 2048 : 2560L * 2048);
    int bx = blockIdx.x * 32, by = blockIdx.y * 32;
    if (bx >= C) return;
    __shared__ unsigned short t[32][33];
    int x = threadIdx.x, y0 = threadIdx.y;
    #pragma unroll
    for (int i = 0; i < 4; i++) {
        int y = y0 + i * 8;
        t[y][x] = f2bf(src[(long)(by + y) * C + bx + x]);
    }
    __syncthreads();
    #pragma unroll
    for (int i = 0; i < 4; i++) {
        int y = y0 + i * 8;
        Wt[doff + (long)(bx + y) * 2048 + by + x] = t[x][y];
    }
}

// single fp32->bf16 transpose (for wo, launched after gemm1 frees Wt)
__global__ void transpose_to_bf16(const float* __restrict__ src,
                                  unsigned short* __restrict__ dst,
                                  int R, int C, long dst_off, int ldd) {
    __shared__ unsigned short t[32][33];
    int bx = blockIdx.x * 32, by = blockIdx.y * 32;
    int x = threadIdx.x, y0 = threadIdx.y;
    #pragma unroll
    for (int i = 0; i < 4; i++) {
        int y = y0 + i * 8;
        t[y][x] = f2bf(src[(long)(by + y) * C + bx + x]);
    }
    __syncthreads();
    #pragma unroll
    for (int i = 0; i < 4; i++) {
        int y = y0 + i * 8;
        dst[dst_off + (long)(bx + y) * ldd + by + x] = t[x][y];
    }
}

// ---------------------------------------------------------------------------
// Prep: X fp32->bf16 (all 4096 blocks), bias concat (blocks 0-11),
// rope table Tab[4096 tokens][64 freqs x (cs,sn) bf16 pairs] (blocks 0-1023).
// ---------------------------------------------------------------------------
__global__ __launch_bounds__(256) void prep_kernel(
        const float* __restrict__ X, unsigned short* __restrict__ Xb,
        const float* __restrict__ bq, const float* __restrict__ bk,
        const float* __restrict__ bv, float* __restrict__ bsf,
        const float* __restrict__ tv, const float* __restrict__ rw,
        unsigned int* __restrict__ Tab) {
    int bi = blockIdx.x, tid = threadIdx.x;
    long i = ((long)bi * 256 + tid) * 8;
    {
        f32x4 a = *(const f32x4*)&X[i];
        f32x4 b = *(const f32x4*)&X[i + 4];
        u32x4 r;
        r.x = (unsigned)f2bf(a[0]) | ((unsigned)f2bf(a[1]) << 16);
        r.y = (unsigned)f2bf(a[2]) | ((unsigned)f2bf(a[3]) << 16);
        r.z = (unsigned)f2bf(b[0]) | ((unsigned)f2bf(b[1]) << 16);
        r.w = (unsigned)f2bf(b[2]) | ((unsigned)f2bf(b[3]) << 16);
        *(u32x4*)&Xb[i] = r;
    }
    if (bi < 12) {
        int ib = bi * 256 + tid;
        bsf[ib] = (ib < 2048) ? bq[ib] : ((ib < 2560) ? bk[ib - 2048] : bv[ib - 2560]);
    }
    if (bi < 1024) {
        int m = bi * 4 + (tid >> 6);
        int fi = tid & 63;
        float t = tv[m];
        float f = t * powf(10000.f, -(float)fi / 64.f) * rw[fi];
        // word = cs (low16) | sn (high16), both bf16
        Tab[m * 64 + fi] = (unsigned)f2bf(cosf(f)) | ((unsigned)f2bf(sinf(f)) << 16);
    }
}

// ---------------------------------------------------------------------------
// GEMM1 + bias + RoPE fused.  A=Xb bf16 [4096][2048], Bt=Wt bf16 [3072][2048].
// Grid (24,32): bx 0..15 -> Q head bx; 16..19 -> K head bx-16; 20..23 -> V.
// R8 epilogue: cos/sin prefetched as bf16 pairs into regs BEFORE the LDS
// passes -> nothing global inside the barrier brackets.
// ---------------------------------------------------------------------------
__global__ __launch_bounds__(256) void gemm_qkv_rope(
        const unsigned short* __restrict__ A,
        const unsigned short* __restrict__ Bt,
        const float* __restrict__ bsf,
        const unsigned int* __restrict__ Tab,
        unsigned short* __restrict__ Qr,
        unsigned short* __restrict__ Kr,
        unsigned short* __restrict__ Vt) {
    __shared__ __align__(16) char smem[32 * 132 * 4];   // 16896 B
    unsigned short* As = (unsigned short*)smem;          // 8192 B
    unsigned short* Bs = (unsigned short*)(smem + 8192); // 8192 B
    float* Ep = (float*)smem;                            // epilogue: 32x132 fp32

    const int tid = threadIdx.x;
    const int wid = tid >> 6, lane = tid & 63, quad = lane >> 4, l16 = lane & 15;
    const int wr = wid >> 1, wc = wid & 1;
    const int m0 = blockIdx.y * 128, n0 = blockIdx.x * 128;
    const int bx = blockIdx.x;

    const int cA = tid, cB = 256 + tid;
    const int rowA = cA >> 2, colA = (cA & 3) * 8;
    const int rowB = cB >> 2, colB = (cB & 3) * 8;

    f32x4 acc[4][4];
    #pragma unroll
    for (int i = 0; i < 4; i++)
        #pragma unroll
        for (int j = 0; j < 4; j++)
            #pragma unroll
            for (int c = 0; c < 4; c++) acc[i][j][c] = 0.f;

    for (int k0 = 0; k0 < 2048; k0 += 32) {
        gload_lds16(&A[(long)(m0 + rowA) * 2048 + k0 + colA], &As[cA * 8]);
        gload_lds16(&A[(long)(m0 + rowB) * 2048 + k0 + colB], &As[cB * 8]);
        gload_lds16(&Bt[(long)(n0 + rowA) * 2048 + k0 + colA], &Bs[cA * 8]);
        gload_lds16(&Bt[(long)(n0 + rowB) * 2048 + k0 + colB], &Bs[cB * 8]);
        __syncthreads();
        bf16x8 af[4], bfr[4];
        #pragma unroll
        for (int mi = 0; mi < 4; mi++)
            af[mi] = *(const bf16x8*)&As[(wr * 64 + mi * 16 + l16) * 32 + quad * 8];
        #pragma unroll
        for (int ni = 0; ni < 4; ni++)
            bfr[ni] = *(const bf16x8*)&Bs[(wc * 64 + ni * 16 + l16) * 32 + quad * 8];
        #pragma unroll
        for (int mi = 0; mi < 4; mi++)
            #pragma unroll
            for (int ni = 0; ni < 4; ni++)
                acc[mi][ni] = __builtin_amdgcn_mfma_f32_16x16x32_bf16(
                    af[mi], bfr[ni], acc[mi][ni], 0, 0, 0);
        __syncthreads();
    }

    // ---- fused epilogue ----
    float bv4[4];
    #pragma unroll
    for (int ni = 0; ni < 4; ni++) bv4[ni] = bsf[n0 + wc * 64 + ni * 16 + l16];
    const bool isV = (bx >= 20);

    // epilogue thread mapping (rope path): row lr 0..31, col-octet jj 0..7
    const int lr = tid >> 3, jj = tid & 7, j0 = jj * 8;

    // Prefetch rope table for all 4 mi passes: tq[mi][g] covers freqs
    // j0+4g..j0+4g+3 as (cs|sn) bf16-pair words.
    u32x4 tq[4][2];
    if (!isV) {
        #pragma unroll
        for (int mi = 0; mi < 4; mi++) {
            int gm = m0 + ((lr >> 4) << 6) + mi * 16 + (lr & 15);
            tq[mi][0] = *(const u32x4*)&Tab[(long)gm * 64 + j0];
            tq[mi][1] = *(const u32x4*)&Tab[(long)gm * 64 + j0 + 4];
        }
    }

    #pragma unroll
    for (int mi = 0; mi < 4; mi++) {
        // phase1: acc + bias -> Ep[e][col], e = wr*16+quad*4+r
        #pragma unroll
        for (int ni = 0; ni < 4; ni++)
            #pragma unroll
            for (int r = 0; r < 4; r++)
                Ep[(wr * 16 + quad * 4 + r) * 132 + wc * 64 + ni * 16 + l16] =
                    acc[mi][ni][r] + bv4[ni];
        __syncthreads();
        if (!isV) {
            const int gm = m0 + ((lr >> 4) << 6) + mi * 16 + (lr & 15);
            const int bb = gm >> 11, s = gm & 2047;
            unsigned short* dst = (bx < 16)
                ? Qr + ((long)(bb * NH + bx) * S_LEN + s) * HD
                : Kr + ((long)(bb * NKV + (bx - 16)) * S_LEN + s) * HD;
            f32x4 x1a = *(f32x4*)&Ep[lr * 132 + j0];
            f32x4 x1b = *(f32x4*)&Ep[lr * 132 + j0 + 4];
            f32x4 x2a = *(f32x4*)&Ep[lr * 132 + 64 + j0];
            f32x4 x2b = *(f32x4*)&Ep[lr * 132 + 64 + j0 + 4];
            f32x4 la, lb, ha, hb;
            #pragma unroll
            for (int e = 0; e < 4; e++) {
                float ca = __builtin_bit_cast(float, tq[mi][0][e] << 16);
                float sa = __builtin_bit_cast(float, tq[mi][0][e] & 0xffff0000u);
                float cb = __builtin_bit_cast(float, tq[mi][1][e] << 16);
                float sb = __builtin_bit_cast(float, tq[mi][1][e] & 0xffff0000u);
                la[e] = x1a[e] * ca - x2a[e] * sa;
                ha[e] = x2a[e] * ca + x1a[e] * sa;
                lb[e] = x1b[e] * cb - x2b[e] * sb;
                hb[e] = x2b[e] * cb + x1b[e] * sb;
            }
            u32x4 lo, hi;
            lo.x = (unsigned)f2bf(la[0]) | ((unsigned)f2bf(la[1]) << 16);
            lo.y = (unsigned)f2bf(la[2]) | ((unsigned)f2bf(la[3]) << 16);
            lo.z = (unsigned)f2bf(lb[0]) | ((unsigned)f2bf(lb[1]) << 16);
            lo.w = (unsigned)f2bf(lb[2]) | ((unsigned)f2bf(lb[3]) << 16);
            hi.x = (unsigned)f2bf(ha[0]) | ((unsigned)f2bf(ha[1]) << 16);
            hi.y = (unsigned)f2bf(ha[2]) | ((unsigned)f2bf(ha[3]) << 16);
            hi.z = (unsigned)f2bf(hb[0]) | ((unsigned)f2bf(hb[1]) << 16);
            hi.w = (unsigned)f2bf(hb[2]) | ((unsigned)f2bf(hb[3]) << 16);
            *(u32x4*)&dst[j0] = lo;
            *(u32x4*)&dst[64 + j0] = hi;
        } else {
            // V: bias only, transposed store Vt[d][s] (16 contiguous s / thread)
            const int d = tid >> 1, sh = tid & 1;
            const int gmb = m0 + sh * 64 + mi * 16;
            const int bb = gmb >> 11, s0 = gmb & 2047;
            unsigned short* dst =
                Vt + ((long)(bb * NKV + (bx - 20)) * HD + d) * S_LEN + s0;
            unsigned short pv[16];
            #pragma unroll
            for (int t = 0; t < 16; t++)
                pv[t] = f2bf(Ep[(sh * 16 + t) * 132 + d]);
            u32x4 v0, v1;
            v0.x = (unsigned)pv[0]  | ((unsigned)pv[1]  << 16);
            v0.y = (unsigned)pv[2]  | ((unsigned)pv[3]  << 16);
            v0.z = (unsigned)pv[4]  | ((unsigned)pv[5]  << 16);
            v0.w = (unsigned)pv[6]  | ((unsigned)pv[7]  << 16);
            v1.x = (unsigned)pv[8]  | ((unsigned)pv[9]  << 16);
            v1.y = (unsigned)pv[10] | ((unsigned)pv[11] << 16);
            v1.z = (unsigned)pv[12] | ((unsigned)pv[13] << 16);
            v1.w = (unsigned)pv[14] | ((unsigned)pv[15] << 16);
            *(u32x4*)&dst[0] = v0;
            *(u32x4*)&dst[8] = v1;
        }
        __syncthreads();   // before next chunk overwrites Ep
    }
}

// ---------------------------------------------------------------------------
// GEMM2 (plain epilogue): C fp32 = AO bf16 x Wt^T.
// ---------------------------------------------------------------------------
template <typename CT>
__global__ __launch_bounds__(256) void gemm_bt_async(
        const unsigned short* __restrict__ A,
        const unsigned short* __restrict__ Bt,
        CT* __restrict__ C,
        const float* __restrict__ bias,
        int K, int lda, int ldb, int ldc) {
    __shared__ __align__(16) unsigned short As[128 * 32];
    __shared__ __align__(16) unsigned short Bs[128 * 32];
    const int tid = threadIdx.x;
    const int wid = tid >> 6, lane = tid & 63, quad = lane >> 4, l16 = lane & 15;
    const int wr = wid >> 1, wc = wid & 1;
    const int m0 = blockIdx.y * 128, n0 = blockIdx.x * 128;

    const int cA = tid, cB = 256 + tid;
    const int rowA = cA >> 2, colA = (cA & 3) * 8;
    const int rowB = cB >> 2, colB = (cB & 3) * 8;

    f32x4 acc[4][4];
    #pragma unroll
    for (int i = 0; i < 4; i++)
        #pragma unroll
        for (int j = 0; j < 4; j++)
            #pragma unroll
            for (int c = 0; c < 4; c++) acc[i][j][c] = 0.f;

    for (int k0 = 0; k0 < K; k0 += 32) {
        gload_lds16(&A[(long)(m0 + rowA) * lda + k0 + colA], &As[cA * 8]);
        gload_lds16(&A[(long)(m0 + rowB) * lda + k0 + colB], &As[cB * 8]);
        gload_lds16(&Bt[(long)(n0 + rowA) * ldb + k0 + colA], &Bs[cA * 8]);
        gload_lds16(&Bt[(long)(n0 + rowB) * ldb + k0 + colB], &Bs[cB * 8]);
        __syncthreads();
        bf16x8 af[4], bfr[4];
        #pragma unroll
        for (int mi = 0; mi < 4; mi++)
            af[mi] = *(const bf16x8*)&As[(wr * 64 + mi * 16 + l16) * 32 + quad * 8];
        #pragma unroll
        for (int ni = 0; ni < 4; ni++)
            bfr[ni] = *(const bf16x8*)&Bs[(wc * 64 + ni * 16 + l16) * 32 + quad * 8];
        #pragma unroll
        for (int mi = 0; mi < 4; mi++)
            #pragma unroll
            for (int ni = 0; ni < 4; ni++)
                acc[mi][ni] = __builtin_amdgcn_mfma_f32_16x16x32_bf16(
                    af[mi], bfr[ni], acc[mi][ni], 0, 0, 0);
        __syncthreads();
    }

    #pragma unroll
    for (int mi = 0; mi < 4; mi++) {
        #pragma unroll
        for (int ni = 0; ni < 4; ni++) {
            int gn = n0 + wc * 64 + ni * 16 + l16;
            float bv_ = bias ? bias[gn] : 0.f;
            #pragma unroll
            for (int r = 0; r < 4; r++) {
                int gm = m0 + wr * 64 + mi * 16 + quad * 4 + r;
                float v = acc[mi][ni][r] + bv_;
                if constexpr (sizeof(CT) == 4) C[(long)gm * ldc + gn] = v;
                else                           C[(long)gm * ldc + gn] = f2bf(v);
            }
        }
    }
}

// ---------------------------------------------------------------------------
// Causal flash attention, GQA, transposed scores.  R8: 256 threads = 4 waves,
// each wave owns 32 q rows (2 q-sets of 16) -> every K/V LDS b128 read feeds
// 2 MFMAs.  Grid (NH, 16, B) unchanged (2 blocks/CU, paired causal schedule).
// ---------------------------------------------------------------------------
__global__ __launch_bounds__(256, 2) void attn_kernel(
        const unsigned short* __restrict__ Qr,
        const unsigned short* __restrict__ Kr,
        const unsigned short* __restrict__ Vt,
        unsigned short* __restrict__ Out) {
    __shared__ __align__(16) unsigned short Ks[64 * 128];
    __shared__ __align__(16) unsigned short Vs[128 * 64];
    __shared__ __align__(16) unsigned short Ps[8][16 * 68];  // [wave*2+set]

    const int h = blockIdx.x, b = blockIdx.z;
    const int qt = b ? blockIdx.y : (int)(gridDim.y - 1 - blockIdx.y);
    const int tid = threadIdx.x, w = tid >> 6, lane = tid & 63;
    const int quad = lane >> 4, l16 = lane & 15;
    const int hk = h >> 2;
    const unsigned short* Qb = Qr + (long)((b * NH + h) * S_LEN) * HD;
    const unsigned short* Kb = Kr + (long)((b * NKV + hk) * S_LEN) * HD;
    const unsigned short* Vb = Vt + (long)((b * NKV + hk) * HD) * S_LEN;
    const int qw = qt * 128 + w * 32;        // wave owns rows qw..qw+31
    const float sl2 = 0.08838834764831845f * 1.4426950408889634f;
    const float MASK_MIN = -3.0e38f;

    bf16x8 qf[2][4];
    #pragma unroll
    for (int s = 0; s < 2; s++)
        #pragma unroll
        for (int kc = 0; kc < 4; kc++)
            qf[s][kc] = *(const bf16x8*)
                &Qb[(long)(qw + s * 16 + l16) * HD + kc * 32 + quad * 8];

    f32x4 o[2][8];
    #pragma unroll
    for (int s = 0; s < 2; s++)
        #pragma unroll
        for (int db = 0; db < 8; db++)
            #pragma unroll
            for (int c = 0; c < 4; c++) o[s][db][c] = 0.f;
    float rm[2] = {MASK_MIN, MASK_MIN}, rl[2] = {0.f, 0.f};

    const int nkt = 2 * qt + 2;
    for (int kt = 0; kt < nkt; kt++) {
        const int k0 = kt * 64;
        __syncthreads();
        #pragma unroll
        for (int i = 0; i < 4; i++) {
            int c = tid + 256 * i;
            int kR = c >> 4, kC = ((c & 15) ^ (kR & 15)) * 8;
            gload_lds16(&Kb[(long)(k0 + kR) * HD + kC], &Ks[c * 8]);
        }
        #pragma unroll
        for (int i = 0; i < 4; i++) {
            int c = tid + 256 * i;
            int vR = c >> 3, vC = ((c & 7) ^ (vR & 7)) * 8;
            gload_lds16(&Vb[(long)vR * S_LEN + k0 + vC], &Vs[c * 8]);
        }
        __syncthreads();

        if (k0 > qw + 31) continue;          // fully masked for this wave

        // ---- S^T both q-sets; each kf read feeds 2 MFMAs ----
        f32x4 sc[2][4];
        #pragma unroll
        for (int nb = 0; nb < 4; nb++) {
            #pragma unroll
            for (int c = 0; c < 4; c++) { sc[0][nb][c] = 0.f; sc[1][nb][c] = 0.f; }
            #pragma unroll
            for (int kc = 0; kc < 4; kc++) {
                bf16x8 kf = *(const bf16x8*)
                    &Ks[(nb * 16 + l16) * 128 + (((kc * 4 + quad) ^ l16) * 8)];
                sc[0][nb] = __builtin_amdgcn_mfma_f32_16x16x32_bf16(kf, qf[0][kc], sc[0][nb], 0, 0, 0);
                sc[1][nb] = __builtin_amdgcn_mfma_f32_16x16x32_bf16(kf, qf[1][kc], sc[1][nb], 0, 0, 0);
            }
        }
        // ---- scale + mask + per-lane online softmax per set ----
        #pragma unroll
        for (int s = 0; s < 2; s++) {
            const int qws = qw + s * 16;
            const int q = qws + l16;
            if (k0 + 63 > qws) {             // diagonal region for this set
                #pragma unroll
                for (int nb = 0; nb < 4; nb++) {
                    int kvb = k0 + nb * 16 + quad * 4;
                    #pragma unroll
                    for (int r = 0; r < 4; r++) {
                        float v = sc[s][nb][r] * sl2;
                        sc[s][nb][r] = (kvb + r > q) ? MASK_MIN : v;
                    }
                }
            } else {
                #pragma unroll
                for (int nb = 0; nb < 4; nb++)
                    #pragma unroll
                    for (int r = 0; r < 4; r++) sc[s][nb][r] *= sl2;
            }
            float tm = MASK_MIN;
            #pragma unroll
            for (int nb = 0; nb < 4; nb++)
                #pragma unroll
                for (int r = 0; r < 4; r++) tm = fmaxf(tm, sc[s][nb][r]);
            tm = fmaxf(tm, __shfl_xor(tm, 16));
            tm = fmaxf(tm, __shfl_xor(tm, 32));
            float mn = fmaxf(rm[s], tm);
            float alpha = exp2f(rm[s] - mn);
            rm[s] = mn;
            float rs = 0.f;
            #pragma unroll
            for (int nb = 0; nb < 4; nb++) {
                float pv0 = exp2f(sc[s][nb][0] - mn), pv1 = exp2f(sc[s][nb][1] - mn);
                float pv2 = exp2f(sc[s][nb][2] - mn), pv3 = exp2f(sc[s][nb][3] - mn);
                rs += (pv0 + pv1) + (pv2 + pv3);
                u32x2 pk;
                pk.x = (unsigned)f2bf(pv0) | ((unsigned)f2bf(pv1) << 16);
                pk.y = (unsigned)f2bf(pv2) | ((unsigned)f2bf(pv3) << 16);
                *(u32x2*)&Ps[w * 2 + s][l16 * 68 + nb * 16 + quad * 4] = pk;
            }
            rs += __shfl_xor(rs, 16);
            rs += __shfl_xor(rs, 32);
            rl[s] = rl[s] * alpha + rs;
            #pragma unroll
            for (int db = 0; db < 8; db++)
                #pragma unroll
                for (int c = 0; c < 4; c++) o[s][db][c] *= alpha;
        }
        // (Ps rows private to this wave; lgkmcnt orders write->read)

        // ---- O^T += V^T P^T; each vf read feeds 2 MFMAs ----
        #pragma unroll
        for (int kk = 0; kk < 2; kk++) {
            bf16x8 pf0 = *(const bf16x8*)&Ps[w * 2 + 0][l16 * 68 + kk * 32 + quad * 8];
            bf16x8 pf1 = *(const bf16x8*)&Ps[w * 2 + 1][l16 * 68 + kk * 32 + quad * 8];
            #pragma unroll
            for (int db = 0; db < 8; db++) {
                bf16x8 vf = *(const bf16x8*)
                    &Vs[(db * 16 + l16) * 64 + (((kk * 4 + quad) ^ (l16 & 7)) * 8)];
                o[0][db] = __builtin_amdgcn_mfma_f32_16x16x32_bf16(vf, pf0, o[0][db], 0, 0, 0);
                o[1][db] = __builtin_amdgcn_mfma_f32_16x16x32_bf16(vf, pf1, o[1][db], 0, 0, 0);
            }
        }
    }

    // ---- epilogue ----
    #pragma unroll
    for (int s = 0; s < 2; s++) {
        float inv_l = 1.0f / rl[s];
        int q = qw + s * 16 + l16;
        long obase = (long)(b * S_LEN + q) * 2048 + h * 128 + quad * 4;
        #pragma unroll
        for (int db = 0; db < 8; db++) {
            u32x2 pk;
            pk.x = (unsigned)f2bf(o[s][db][0] * inv_l) |
                   ((unsigned)f2bf(o[s][db][1] * inv_l) << 16);
            pk.y = (unsigned)f2bf(o[s][db][2] * inv_l) |
                   ((unsigned)f2bf(o[s][db][3] * inv_l) << 16);
            *(u32x2*)&Out[obase + db * 16] = pk;
        }
    }
}

// ---------------------------------------------------------------------------
extern "C" void kernel_launch(void* const* d_in, const int* in_sizes, int n_in,
                              void* d_out, int out_size, void* d_ws, size_t ws_size,
                              hipStream_t stream) {
    const float* X  = (const float*)d_in[0];
    const float* tv = (const float*)d_in[1];
    const float* wq = (const float*)d_in[2];
    const float* bq = (const float*)d_in[3];
    const float* wk = (const float*)d_in[4];
    const float* bk = (const float*)d_in[5];
    const float* wv = (const float*)d_in[6];
    const float* bv = (const float*)d_in[7];
    const float* wo = (const float*)d_in[8];
    const float* rw = (const float*)d_in[9];

    // Workspace (~56 MB):
    //   Wt 12.6MB ([wq|wk|wv]^T -> reused for wo^T after gemm1)
    //   bsf 12KB, Tab 1MB, Qr 16.8MB, Kr/Vt 8.4MB, AO 16.8MB (=Xb alias)
    char* ws = (char*)d_ws;
    unsigned short* Wt  = (unsigned short*)ws; ws += 3072L * 2048 * 2;
    float*          bsf = (float*)ws;          ws += 3072L * 4;
    unsigned int*   Tab = (unsigned int*)ws;   ws += 4096L * 64 * 4;
    unsigned short* Qr  = (unsigned short*)ws; ws += (long)BATCH * NH  * S_LEN * HD * 2;
    unsigned short* Kr  = (unsigned short*)ws; ws += (long)BATCH * NKV * S_LEN * HD * 2;
    unsigned short* Vt  = (unsigned short*)ws; ws += (long)BATCH * NKV * HD * S_LEN * 2;
    unsigned short* AO  = (unsigned short*)ws; ws += 4096L * 2048 * 2;
    unsigned short* Xb  = AO;   // alias: Xb dead (post-gemm1) before attn writes AO

    transpose_qkv<<<dim3(64, 64, 3), dim3(32, 8), 0, stream>>>(wq, wk, wv, Wt);
    prep_kernel<<<4096, 256, 0, stream>>>(X, Xb, bq, bk, bv, bsf, tv, rw, Tab);
    gemm_qkv_rope<<<dim3(24, 32), 256, 0, stream>>>(Xb, Wt, bsf, Tab, Qr, Kr, Vt);
    transpose_to_bf16<<<dim3(64, 64), dim3(32, 8), 0, stream>>>(wo, Wt, 2048, 2048, 0L, 2048);
    attn_kernel<<<dim3(NH, S_LEN / 128, BATCH), 256, 0, stream>>>(Qr, Kr, Vt, AO);
    gemm_bt_async<float><<<dim3(16, 32), 256, 0, stream>>>(
        AO, Wt, (float*)d_out, nullptr, 2048, 2048, 2048, 2048);
}

// Round 9
// 343.712 us; speedup vs baseline: 1.0627x; 1.0627x over previous
//
#include <hip/hip_runtime.h>

// ---------------------------------------------------------------------------
// TimeMoeAttention: X@Wq/Wk/Wv + bias -> continuous-time RoPE -> causal GQA
// attention -> @Wo.  B=2, S=2048, H=2048, NH=16, NKV=4, HD=128.
// I/O fp32; internal bf16 + fp32 MFMA accumulation.
// R9: attn reverted to R7 512-thread form (R8's 2-q-set lost TLP);
//     softmax scale folded into Q at gemm1 epilogue (attn mul removal);
//     GEMM LDS fragment layout XOR-swizzled -> 2-way max bank aliasing.
// ---------------------------------------------------------------------------

#define S_LEN 2048
#define BATCH 2
#define NH    16
#define NKV   4
#define HD    128

typedef float  f32x4  __attribute__((ext_vector_type(4)));
typedef __bf16 bf16x8 __attribute__((ext_vector_type(8)));
typedef unsigned int u32x4 __attribute__((ext_vector_type(4)));
typedef unsigned int u32x2 __attribute__((ext_vector_type(2)));

__device__ inline unsigned short f2bf(float f) {
    unsigned u = __builtin_bit_cast(unsigned, f);
    unsigned r = (u + 0x7fffu + ((u >> 16) & 1u)) >> 16;   // RNE
    return (unsigned short)r;
}

// async global->LDS, 16 bytes per lane (dest = wave-uniform base + lane*16)
__device__ inline void gload_lds16(const void* g, void* l) {
    __builtin_amdgcn_global_load_lds(
        (const __attribute__((address_space(1))) unsigned int*)g,
        (__attribute__((address_space(3))) unsigned int*)l, 16, 0, 0);
}

// ---------------------------------------------------------------------------
// Fused transposes: wq|wk|wv (fp32) -> Wt (bf16, [3072][2048]).  z selects.
// ---------------------------------------------------------------------------
__global__ void transpose_qkv(const float* __restrict__ wq,
                              const float* __restrict__ wk,
                              const float* __restrict__ wv,
                              unsigned short* __restrict__ Wt) {
    int z = blockIdx.z;
    const float* src = (z == 0) ? wq : ((z == 1) ? wk : wv);
    int C = (z == 0) ? 2048 : 512;
    long doff = (z == 0) ? 0L : ((z == 1) ? 2048L * 2048 : 2560L * 2048);
    int bx = blockIdx.x * 32, by = blockIdx.y * 32;
    if (bx >= C) return;
    __shared__ unsigned short t[32][33];
    int x = threadIdx.x, y0 = threadIdx.y;
    #pragma unroll
    for (int i = 0; i < 4; i++) {
        int y = y0 + i * 8;
        t[y][x] = f2bf(src[(long)(by + y) * C + bx + x]);
    }
    __syncthreads();
    #pragma unroll
    for (int i = 0; i < 4; i++) {
        int y = y0 + i * 8;
        Wt[doff + (long)(bx + y) * 2048 + by + x] = t[x][y];
    }
}

// single fp32->bf16 transpose (for wo, launched after gemm1 frees Wt)
__global__ void transpose_to_bf16(const float* __restrict__ src,
                                  unsigned short* __restrict__ dst,
                                  int R, int C, long dst_off, int ldd) {
    __shared__ unsigned short t[32][33];
    int bx = blockIdx.x * 32, by = blockIdx.y * 32;
    int x = threadIdx.x, y0 = threadIdx.y;
    #pragma unroll
    for (int i = 0; i < 4; i++) {
        int y = y0 + i * 8;
        t[y][x] = f2bf(src[(long)(by + y) * C + bx + x]);
    }
    __syncthreads();
    #pragma unroll
    for (int i = 0; i < 4; i++) {
        int y = y0 + i * 8;
        dst[dst_off + (long)(bx + y) * ldd + by + x] = t[x][y];
    }
}

// ---------------------------------------------------------------------------
// Prep: X fp32->bf16 (all 4096 blocks), bias concat (blocks 0-11),
// rope table Tab[4096 tokens][64 freqs x (cs,sn) bf16 pairs] (blocks 0-1023).
// ---------------------------------------------------------------------------
__global__ __launch_bounds__(256) void prep_kernel(
        const float* __restrict__ X, unsigned short* __restrict__ Xb,
        const float* __restrict__ bq, const float* __restrict__ bk,
        const float* __restrict__ bv, float* __restrict__ bsf,
        const float* __restrict__ tv, const float* __restrict__ rw,
        unsigned int* __restrict__ Tab) {
    int bi = blockIdx.x, tid = threadIdx.x;
    long i = ((long)bi * 256 + tid) * 8;
    {
        f32x4 a = *(const f32x4*)&X[i];
        f32x4 b = *(const f32x4*)&X[i + 4];
        u32x4 r;
        r.x = (unsigned)f2bf(a[0]) | ((unsigned)f2bf(a[1]) << 16);
        r.y = (unsigned)f2bf(a[2]) | ((unsigned)f2bf(a[3]) << 16);
        r.z = (unsigned)f2bf(b[0]) | ((unsigned)f2bf(b[1]) << 16);
        r.w = (unsigned)f2bf(b[2]) | ((unsigned)f2bf(b[3]) << 16);
        *(u32x4*)&Xb[i] = r;
    }
    if (bi < 12) {
        int ib = bi * 256 + tid;
        bsf[ib] = (ib < 2048) ? bq[ib] : ((ib < 2560) ? bk[ib - 2048] : bv[ib - 2560]);
    }
    if (bi < 1024) {
        int m = bi * 4 + (tid >> 6);
        int fi = tid & 63;
        float t = tv[m];
        float f = t * powf(10000.f, -(float)fi / 64.f) * rw[fi];
        Tab[m * 64 + fi] = (unsigned)f2bf(cosf(f)) | ((unsigned)f2bf(sinf(f)) << 16);
    }
}

// ---------------------------------------------------------------------------
// GEMM1 + bias + RoPE fused.  A=Xb bf16 [4096][2048], Bt=Wt bf16 [3072][2048].
// Grid (24,32): bx 0..15 -> Q head bx; 16..19 -> K head bx-16; 20..23 -> V.
// R9: LDS slot c holds data-oct (c&3)^((c>>3)&3); frag read at quad^((l16>>1)&3)
//     -> 2-way max bank aliasing (free).  Q heads pre-scaled by scale*log2e.
// ---------------------------------------------------------------------------
__global__ __launch_bounds__(256) void gemm_qkv_rope(
        const unsigned short* __restrict__ A,
        const unsigned short* __restrict__ Bt,
        const float* __restrict__ bsf,
        const unsigned int* __restrict__ Tab,
        unsigned short* __restrict__ Qr,
        unsigned short* __restrict__ Kr,
        unsigned short* __restrict__ Vt) {
    __shared__ __align__(16) char smem[32 * 132 * 4];   // 16896 B
    unsigned short* As = (unsigned short*)smem;          // 8192 B
    unsigned short* Bs = (unsigned short*)(smem + 8192); // 8192 B
    float* Ep = (float*)smem;                            // epilogue: 32x132 fp32

    const int tid = threadIdx.x;
    const int wid = tid >> 6, lane = tid & 63, quad = lane >> 4, l16 = lane & 15;
    const int wr = wid >> 1, wc = wid & 1;
    const int m0 = blockIdx.y * 128, n0 = blockIdx.x * 128;
    const int bx = blockIdx.x;

    // staging: slot c -> row c>>2, data-oct (c&3)^((c>>3)&3)
    const int cA = tid, cB = 256 + tid;
    const int rowA = cA >> 2, octA = ((cA & 3) ^ ((cA >> 3) & 3)) * 8;
    const int rowB = cB >> 2, octB = ((cB & 3) ^ ((cB >> 3) & 3)) * 8;
    const int sw = (l16 >> 1) & 3;           // read-side swizzle

    f32x4 acc[4][4];
    #pragma unroll
    for (int i = 0; i < 4; i++)
        #pragma unroll
        for (int j = 0; j < 4; j++)
            #pragma unroll
            for (int c = 0; c < 4; c++) acc[i][j][c] = 0.f;

    for (int k0 = 0; k0 < 2048; k0 += 32) {
        gload_lds16(&A[(long)(m0 + rowA) * 2048 + k0 + octA], &As[cA * 8]);
        gload_lds16(&A[(long)(m0 + rowB) * 2048 + k0 + octB], &As[cB * 8]);
        gload_lds16(&Bt[(long)(n0 + rowA) * 2048 + k0 + octA], &Bs[cA * 8]);
        gload_lds16(&Bt[(long)(n0 + rowB) * 2048 + k0 + octB], &Bs[cB * 8]);
        __syncthreads();
        bf16x8 af[4], bfr[4];
        #pragma unroll
        for (int mi = 0; mi < 4; mi++)
            af[mi] = *(const bf16x8*)
                &As[(wr * 64 + mi * 16 + l16) * 32 + ((quad ^ sw)) * 8];
        #pragma unroll
        for (int ni = 0; ni < 4; ni++)
            bfr[ni] = *(const bf16x8*)
                &Bs[(wc * 64 + ni * 16 + l16) * 32 + ((quad ^ sw)) * 8];
        #pragma unroll
        for (int mi = 0; mi < 4; mi++)
            #pragma unroll
            for (int ni = 0; ni < 4; ni++)
                acc[mi][ni] = __builtin_amdgcn_mfma_f32_16x16x32_bf16(
                    af[mi], bfr[ni], acc[mi][ni], 0, 0, 0);
        __syncthreads();
    }
    // NOTE: swizzle permutes which k-octet each frag register set holds, but
    // MFMA accumulates over all 4 kc octets -> sum unchanged (order-invariant
    // in fp32 accumulate per-octet?  No: each MFMA's A and B frags must match
    // k-range.  af[mi] and bfr[ni] use the SAME (quad^sw) octet for the same
    // lane -> A-k and B-k ranges coincide per lane/quad -> product correct.)

    // ---- fused epilogue ----
    float bv4[4];
    #pragma unroll
    for (int ni = 0; ni < 4; ni++) bv4[ni] = bsf[n0 + wc * 64 + ni * 16 + l16];
    const bool isV = (bx >= 20);
    // Q heads: fold softmax scale * log2(e) into stored values
    const float qs = (bx < 16) ? (0.08838834764831845f * 1.4426950408889634f) : 1.0f;

    const int lr = tid >> 3, jj = tid & 7, j0 = jj * 8;

    u32x4 tq[4][2];
    if (!isV) {
        #pragma unroll
        for (int mi = 0; mi < 4; mi++) {
            int gm = m0 + ((lr >> 4) << 6) + mi * 16 + (lr & 15);
            tq[mi][0] = *(const u32x4*)&Tab[(long)gm * 64 + j0];
            tq[mi][1] = *(const u32x4*)&Tab[(long)gm * 64 + j0 + 4];
        }
    }

    #pragma unroll
    for (int mi = 0; mi < 4; mi++) {
        #pragma unroll
        for (int ni = 0; ni < 4; ni++)
            #pragma unroll
            for (int r = 0; r < 4; r++)
                Ep[(wr * 16 + quad * 4 + r) * 132 + wc * 64 + ni * 16 + l16] =
                    acc[mi][ni][r] + bv4[ni];
        __syncthreads();
        if (!isV) {
            const int gm = m0 + ((lr >> 4) << 6) + mi * 16 + (lr & 15);
            const int bb = gm >> 11, s = gm & 2047;
            unsigned short* dst = (bx < 16)
                ? Qr + ((long)(bb * NH + bx) * S_LEN + s) * HD
                : Kr + ((long)(bb * NKV + (bx - 16)) * S_LEN + s) * HD;
            f32x4 x1a = *(f32x4*)&Ep[lr * 132 + j0];
            f32x4 x1b = *(f32x4*)&Ep[lr * 132 + j0 + 4];
            f32x4 x2a = *(f32x4*)&Ep[lr * 132 + 64 + j0];
            f32x4 x2b = *(f32x4*)&Ep[lr * 132 + 64 + j0 + 4];
            f32x4 la, lb, ha, hb;
            #pragma unroll
            for (int e = 0; e < 4; e++) {
                float ca = __builtin_bit_cast(float, tq[mi][0][e] << 16);
                float sa = __builtin_bit_cast(float, tq[mi][0][e] & 0xffff0000u);
                float cb = __builtin_bit_cast(float, tq[mi][1][e] << 16);
                float sb = __builtin_bit_cast(float, tq[mi][1][e] & 0xffff0000u);
                la[e] = (x1a[e] * ca - x2a[e] * sa) * qs;
                ha[e] = (x2a[e] * ca + x1a[e] * sa) * qs;
                lb[e] = (x1b[e] * cb - x2b[e] * sb) * qs;
                hb[e] = (x2b[e] * cb + x1b[e] * sb) * qs;
            }
            u32x4 lo, hi;
            lo.x = (unsigned)f2bf(la[0]) | ((unsigned)f2bf(la[1]) << 16);
            lo.y = (unsigned)f2bf(la[2]) | ((unsigned)f2bf(la[3]) << 16);
            lo.z = (unsigned)f2bf(lb[0]) | ((unsigned)f2bf(lb[1]) << 16);
            lo.w = (unsigned)f2bf(lb[2]) | ((unsigned)f2bf(lb[3]) << 16);
            hi.x = (unsigned)f2bf(ha[0]) | ((unsigned)f2bf(ha[1]) << 16);
            hi.y = (unsigned)f2bf(ha[2]) | ((unsigned)f2bf(ha[3]) << 16);
            hi.z = (unsigned)f2bf(hb[0]) | ((unsigned)f2bf(hb[1]) << 16);
            hi.w = (unsigned)f2bf(hb[2]) | ((unsigned)f2bf(hb[3]) << 16);
            *(u32x4*)&dst[j0] = lo;
            *(u32x4*)&dst[64 + j0] = hi;
        } else {
            const int d = tid >> 1, sh = tid & 1;
            const int gmb = m0 + sh * 64 + mi * 16;
            const int bb = gmb >> 11, s0 = gmb & 2047;
            unsigned short* dst =
                Vt + ((long)(bb * NKV + (bx - 20)) * HD + d) * S_LEN + s0;
            unsigned short pv[16];
            #pragma unroll
            for (int t = 0; t < 16; t++)
                pv[t] = f2bf(Ep[(sh * 16 + t) * 132 + d]);
            u32x4 v0, v1;
            v0.x = (unsigned)pv[0]  | ((unsigned)pv[1]  << 16);
            v0.y = (unsigned)pv[2]  | ((unsigned)pv[3]  << 16);
            v0.z = (unsigned)pv[4]  | ((unsigned)pv[5]  << 16);
            v0.w = (unsigned)pv[6]  | ((unsigned)pv[7]  << 16);
            v1.x = (unsigned)pv[8]  | ((unsigned)pv[9]  << 16);
            v1.y = (unsigned)pv[10] | ((unsigned)pv[11] << 16);
            v1.z = (unsigned)pv[12] | ((unsigned)pv[13] << 16);
            v1.w = (unsigned)pv[14] | ((unsigned)pv[15] << 16);
            *(u32x4*)&dst[0] = v0;
            *(u32x4*)&dst[8] = v1;
        }
        __syncthreads();
    }
}

// ---------------------------------------------------------------------------
// GEMM2: d_out fp32 = AO bf16 x WoT^T.  Same swizzled-LDS K-loop.
// ---------------------------------------------------------------------------
template <typename CT>
__global__ __launch_bounds__(256) void gemm_bt_async(
        const unsigned short* __restrict__ A,
        const unsigned short* __restrict__ Bt,
        CT* __restrict__ C,
        const float* __restrict__ bias,
        int K, int lda, int ldb, int ldc) {
    __shared__ __align__(16) unsigned short As[128 * 32];
    __shared__ __align__(16) unsigned short Bs[128 * 32];
    const int tid = threadIdx.x;
    const int wid = tid >> 6, lane = tid & 63, quad = lane >> 4, l16 = lane & 15;
    const int wr = wid >> 1, wc = wid & 1;
    const int m0 = blockIdx.y * 128, n0 = blockIdx.x * 128;

    const int cA = tid, cB = 256 + tid;
    const int rowA = cA >> 2, octA = ((cA & 3) ^ ((cA >> 3) & 3)) * 8;
    const int rowB = cB >> 2, octB = ((cB & 3) ^ ((cB >> 3) & 3)) * 8;
    const int sw = (l16 >> 1) & 3;

    f32x4 acc[4][4];
    #pragma unroll
    for (int i = 0; i < 4; i++)
        #pragma unroll
        for (int j = 0; j < 4; j++)
            #pragma unroll
            for (int c = 0; c < 4; c++) acc[i][j][c] = 0.f;

    for (int k0 = 0; k0 < K; k0 += 32) {
        gload_lds16(&A[(long)(m0 + rowA) * lda + k0 + octA], &As[cA * 8]);
        gload_lds16(&A[(long)(m0 + rowB) * lda + k0 + octB], &As[cB * 8]);
        gload_lds16(&Bt[(long)(n0 + rowA) * ldb + k0 + octA], &Bs[cA * 8]);
        gload_lds16(&Bt[(long)(n0 + rowB) * ldb + k0 + octB], &Bs[cB * 8]);
        __syncthreads();
        bf16x8 af[4], bfr[4];
        #pragma unroll
        for (int mi = 0; mi < 4; mi++)
            af[mi] = *(const bf16x8*)
                &As[(wr * 64 + mi * 16 + l16) * 32 + (quad ^ sw) * 8];
        #pragma unroll
        for (int ni = 0; ni < 4; ni++)
            bfr[ni] = *(const bf16x8*)
                &Bs[(wc * 64 + ni * 16 + l16) * 32 + (quad ^ sw) * 8];
        #pragma unroll
        for (int mi = 0; mi < 4; mi++)
            #pragma unroll
            for (int ni = 0; ni < 4; ni++)
                acc[mi][ni] = __builtin_amdgcn_mfma_f32_16x16x32_bf16(
                    af[mi], bfr[ni], acc[mi][ni], 0, 0, 0);
        __syncthreads();
    }

    #pragma unroll
    for (int mi = 0; mi < 4; mi++) {
        #pragma unroll
        for (int ni = 0; ni < 4; ni++) {
            int gn = n0 + wc * 64 + ni * 16 + l16;
            float bv_ = bias ? bias[gn] : 0.f;
            #pragma unroll
            for (int r = 0; r < 4; r++) {
                int gm = m0 + wr * 64 + mi * 16 + quad * 4 + r;
                float v = acc[mi][ni][r] + bv_;
                if constexpr (sizeof(CT) == 4) C[(long)gm * ldc + gn] = v;
                else                           C[(long)gm * ldc + gn] = f2bf(v);
            }
        }
    }
}

// ---------------------------------------------------------------------------
// Causal flash attention, GQA, transposed scores.  R7 structure restored:
// 512 threads = 8 waves, wave owns 16 q rows; Q is PRE-SCALED by
// scale*log2(e) at gemm1 -> no per-tile scaling VALU here.
// ---------------------------------------------------------------------------
__global__ __launch_bounds__(512, 4) void attn_kernel(
        const unsigned short* __restrict__ Qr,
        const unsigned short* __restrict__ Kr,
        const unsigned short* __restrict__ Vt,
        unsigned short* __restrict__ Out) {
    __shared__ __align__(16) unsigned short Ks[64 * 128];
    __shared__ __align__(16) unsigned short Vs[128 * 64];
    __shared__ __align__(16) unsigned short Ps[8][16 * 68];

    const int h = blockIdx.x, b = blockIdx.z;
    const int qt = b ? blockIdx.y : (int)(gridDim.y - 1 - blockIdx.y);
    const int tid = threadIdx.x, w = tid >> 6, lane = tid & 63;
    const int quad = lane >> 4, l16 = lane & 15;
    const int hk = h >> 2;
    const unsigned short* Qb = Qr + (long)((b * NH + h) * S_LEN) * HD;
    const unsigned short* Kb = Kr + (long)((b * NKV + hk) * S_LEN) * HD;
    const unsigned short* Vb = Vt + (long)((b * NKV + hk) * HD) * S_LEN;
    const int qw = qt * 128 + w * 16;
    const int q  = qw + l16;
    const float MASK_MIN = -3.0e38f;

    bf16x8 qf[4];
    #pragma unroll
    for (int kc = 0; kc < 4; kc++)
        qf[kc] = *(const bf16x8*)&Qb[(long)q * HD + kc * 32 + quad * 8];

    f32x4 o[8];
    #pragma unroll
    for (int db = 0; db < 8; db++)
        #pragma unroll
        for (int c = 0; c < 4; c++) o[db][c] = 0.f;
    float mr = MASK_MIN, lr = 0.f;

    const int sK0 = tid, sK1 = tid + 512;
    const int kR0 = sK0 >> 4, kC0 = ((sK0 & 15) ^ (kR0 & 15)) * 8;
    const int kR1 = sK1 >> 4, kC1 = ((sK1 & 15) ^ (kR1 & 15)) * 8;
    const int vR0 = sK0 >> 3, vC0 = ((sK0 & 7) ^ (vR0 & 7)) * 8;
    const int vR1 = sK1 >> 3, vC1 = ((sK1 & 7) ^ (vR1 & 7)) * 8;

    const int nkt = 2 * qt + 2;
    for (int kt = 0; kt < nkt; kt++) {
        const int k0 = kt * 64;
        __syncthreads();
        gload_lds16(&Kb[(long)(k0 + kR0) * HD + kC0], &Ks[sK0 * 8]);
        gload_lds16(&Kb[(long)(k0 + kR1) * HD + kC1], &Ks[sK1 * 8]);
        gload_lds16(&Vb[(long)vR0 * S_LEN + k0 + vC0], &Vs[sK0 * 8]);
        gload_lds16(&Vb[(long)vR1 * S_LEN + k0 + vC1], &Vs[sK1 * 8]);
        __syncthreads();

        if (k0 > qw + 15) continue;

        f32x4 sc[4];
        #pragma unroll
        for (int nb = 0; nb < 4; nb++) {
            #pragma unroll
            for (int c = 0; c < 4; c++) sc[nb][c] = 0.f;
            #pragma unroll
            for (int kc = 0; kc < 4; kc++) {
                bf16x8 kf = *(const bf16x8*)
                    &Ks[(nb * 16 + l16) * 128 + (((kc * 4 + quad) ^ l16) * 8)];
                sc[nb] = __builtin_amdgcn_mfma_f32_16x16x32_bf16(kf, qf[kc], sc[nb], 0, 0, 0);
            }
        }
        if (k0 + 63 > qw) {   // diagonal tile: mask only (Q pre-scaled)
            #pragma unroll
            for (int nb = 0; nb < 4; nb++) {
                int kvb = k0 + nb * 16 + quad * 4;
                #pragma unroll
                for (int r = 0; r < 4; r++)
                    sc[nb][r] = (kvb + r > q) ? MASK_MIN : sc[nb][r];
            }
        }
        float tm = MASK_MIN;
        #pragma unroll
        for (int nb = 0; nb < 4; nb++)
            #pragma unroll
            for (int r = 0; r < 4; r++) tm = fmaxf(tm, sc[nb][r]);
        tm = fmaxf(tm, __shfl_xor(tm, 16));
        tm = fmaxf(tm, __shfl_xor(tm, 32));
        float mn = fmaxf(mr, tm);
        float alpha = exp2f(mr - mn);
        mr = mn;
        float rs = 0.f;
        #pragma unroll
        for (int nb = 0; nb < 4; nb++) {
            float pv0 = exp2f(sc[nb][0] - mn), pv1 = exp2f(sc[nb][1] - mn);
            float pv2 = exp2f(sc[nb][2] - mn), pv3 = exp2f(sc[nb][3] - mn);
            rs += (pv0 + pv1) + (pv2 + pv3);
            u32x2 pk;
            pk.x = (unsigned)f2bf(pv0) | ((unsigned)f2bf(pv1) << 16);
            pk.y = (unsigned)f2bf(pv2) | ((unsigned)f2bf(pv3) << 16);
            *(u32x2*)&Ps[w][l16 * 68 + nb * 16 + quad * 4] = pk;
        }
        rs += __shfl_xor(rs, 16);
        rs += __shfl_xor(rs, 32);
        lr = lr * alpha + rs;
        #pragma unroll
        for (int db = 0; db < 8; db++)
            #pragma unroll
            for (int c = 0; c < 4; c++) o[db][c] *= alpha;

        #pragma unroll
        for (int kk = 0; kk < 2; kk++) {
            bf16x8 pf = *(const bf16x8*)&Ps[w][l16 * 68 + kk * 32 + quad * 8];
            #pragma unroll
            for (int db = 0; db < 8; db++) {
                bf16x8 vf = *(const bf16x8*)
                    &Vs[(db * 16 + l16) * 64 + (((kk * 4 + quad) ^ (l16 & 7)) * 8)];
                o[db] = __builtin_amdgcn_mfma_f32_16x16x32_bf16(vf, pf, o[db], 0, 0, 0);
            }
        }
    }

    float inv_l = 1.0f / lr;
    long obase = (long)(b * S_LEN + q) * 2048 + h * 128 + quad * 4;
    #pragma unroll
    for (int db = 0; db < 8; db++) {
        u32x2 pk;
        pk.x = (unsigned)f2bf(o[db][0] * inv_l) | ((unsigned)f2bf(o[db][1] * inv_l) << 16);
        pk.y = (unsigned)f2bf(o[db][2] * inv_l) | ((unsigned)f2bf(o[db][3] * inv_l) << 16);
        *(u32x2*)&Out[obase + db * 16] = pk;
    }
}

// ---------------------------------------------------------------------------
extern "C" void kernel_launch(void* const* d_in, const int* in_sizes, int n_in,
                              void* d_out, int out_size, void* d_ws, size_t ws_size,
                              hipStream_t stream) {
    const float* X  = (const float*)d_in[0];
    const float* tv = (const float*)d_in[1];
    const float* wq = (const float*)d_in[2];
    const float* bq = (const float*)d_in[3];
    const float* wk = (const float*)d_in[4];
    const float* bk = (const float*)d_in[5];
    const float* wv = (const float*)d_in[6];
    const float* bv = (const float*)d_in[7];
    const float* wo = (const float*)d_in[8];
    const float* rw = (const float*)d_in[9];

    // Workspace (~56 MB):
    //   Wt 12.6MB ([wq|wk|wv]^T -> reused for wo^T after gemm1)
    //   bsf 12KB, Tab 1MB, Qr 16.8MB, Kr/Vt 8.4MB, AO 16.8MB (=Xb alias)
    char* ws = (char*)d_ws;
    unsigned short* Wt  = (unsigned short*)ws; ws += 3072L * 2048 * 2;
    float*          bsf = (float*)ws;          ws += 3072L * 4;
    unsigned int*   Tab = (unsigned int*)ws;   ws += 4096L * 64 * 4;
    unsigned short* Qr  = (unsigned short*)ws; ws += (long)BATCH * NH  * S_LEN * HD * 2;
    unsigned short* Kr  = (unsigned short*)ws; ws += (long)BATCH * NKV * S_LEN * HD * 2;
    unsigned short* Vt  = (unsigned short*)ws; ws += (long)BATCH * NKV * HD * S_LEN * 2;
    unsigned short* AO  = (unsigned short*)ws; ws += 4096L * 2048 * 2;
    unsigned short* Xb  = AO;   // alias: Xb dead (post-gemm1) before attn writes AO

    transpose_qkv<<<dim3(64, 64, 3), dim3(32, 8), 0, stream>>>(wq, wk, wv, Wt);
    prep_kernel<<<4096, 256, 0, stream>>>(X, Xb, bq, bk, bv, bsf, tv, rw, Tab);
    gemm_qkv_rope<<<dim3(24, 32), 256, 0, stream>>>(Xb, Wt, bsf, Tab, Qr, Kr, Vt);
    transpose_to_bf16<<<dim3(64, 64), dim3(32, 8), 0, stream>>>(wo, Wt, 2048, 2048, 0L, 2048);
    attn_kernel<<<dim3(NH, S_LEN / 128, BATCH), 512, 0, stream>>>(Qr, Kr, Vt, AO);
    gemm_bt_async<float><<<dim3(16, 32), 256, 0, stream>>>(
        AO, Wt, (float*)d_out, nullptr, 2048, 2048, 2048, 2048);
}

// Round 10
// 325.772 us; speedup vs baseline: 1.1213x; 1.0551x over previous
//
#include <hip/hip_runtime.h>

// ---------------------------------------------------------------------------
// TimeMoeAttention: X@Wq/Wk/Wv + bias -> continuous-time RoPE -> causal GQA
// attention -> @Wo.  B=2, S=2048, H=2048, NH=16, NKV=4, HD=128.
// I/O fp32; internal bf16 + fp32 MFMA accumulation.
// R10: GEMMs use BK=64 (half the barrier-drain events; swizzled LDS, 32KB,
//      occupancy unchanged at 3 blocks/CU); attn adds wave-uniform rescale
//      skip (__any) and HW-packed bf16 converts.
// ---------------------------------------------------------------------------

#define S_LEN 2048
#define BATCH 2
#define NH    16
#define NKV   4
#define HD    128

typedef float  f32x4  __attribute__((ext_vector_type(4)));
typedef __bf16 bf16x8 __attribute__((ext_vector_type(8)));
typedef __bf16 bf16x4 __attribute__((ext_vector_type(4)));
typedef unsigned int u32x4 __attribute__((ext_vector_type(4)));
typedef unsigned int u32x2 __attribute__((ext_vector_type(2)));

__device__ inline unsigned short f2bf(float f) {
    unsigned u = __builtin_bit_cast(unsigned, f);
    unsigned r = (u + 0x7fffu + ((u >> 16) & 1u)) >> 16;   // RNE
    return (unsigned short)r;
}

// async global->LDS, 16 bytes per lane (dest = wave-uniform base + lane*16)
__device__ inline void gload_lds16(const void* g, void* l) {
    __builtin_amdgcn_global_load_lds(
        (const __attribute__((address_space(1))) unsigned int*)g,
        (__attribute__((address_space(3))) unsigned int*)l, 16, 0, 0);
}

// ---------------------------------------------------------------------------
// Fused transposes: wq|wk|wv (fp32) -> Wt (bf16, [3072][2048]).  z selects.
// ---------------------------------------------------------------------------
__global__ void transpose_qkv(const float* __restrict__ wq,
                              const float* __restrict__ wk,
                              const float* __restrict__ wv,
                              unsigned short* __restrict__ Wt) {
    int z = blockIdx.z;
    const float* src = (z == 0) ? wq : ((z == 1) ? wk : wv);
    int C = (z == 0) ? 2048 : 512;
    long doff = (z == 0) ? 0L : ((z == 1) ? 2048L * 2048 : 2560L * 2048);
    int bx = blockIdx.x * 32, by = blockIdx.y * 32;
    if (bx >= C) return;
    __shared__ unsigned short t[32][33];
    int x = threadIdx.x, y0 = threadIdx.y;
    #pragma unroll
    for (int i = 0; i < 4; i++) {
        int y = y0 + i * 8;
        t[y][x] = f2bf(src[(long)(by + y) * C + bx + x]);
    }
    __syncthreads();
    #pragma unroll
    for (int i = 0; i < 4; i++) {
        int y = y0 + i * 8;
        Wt[doff + (long)(bx + y) * 2048 + by + x] = t[x][y];
    }
}

// single fp32->bf16 transpose (for wo, launched after gemm1 frees Wt)
__global__ void transpose_to_bf16(const float* __restrict__ src,
                                  unsigned short* __restrict__ dst,
                                  int R, int C, long dst_off, int ldd) {
    __shared__ unsigned short t[32][33];
    int bx = blockIdx.x * 32, by = blockIdx.y * 32;
    int x = threadIdx.x, y0 = threadIdx.y;
    #pragma unroll
    for (int i = 0; i < 4; i++) {
        int y = y0 + i * 8;
        t[y][x] = f2bf(src[(long)(by + y) * C + bx + x]);
    }
    __syncthreads();
    #pragma unroll
    for (int i = 0; i < 4; i++) {
        int y = y0 + i * 8;
        dst[dst_off + (long)(bx + y) * ldd + by + x] = t[x][y];
    }
}

// ---------------------------------------------------------------------------
// Prep: X fp32->bf16 (all 4096 blocks), bias concat (blocks 0-11),
// rope table Tab[4096 tokens][64 freqs x (cs,sn) bf16 pairs] (blocks 0-1023).
// ---------------------------------------------------------------------------
__global__ __launch_bounds__(256) void prep_kernel(
        const float* __restrict__ X, unsigned short* __restrict__ Xb,
        const float* __restrict__ bq, const float* __restrict__ bk,
        const float* __restrict__ bv, float* __restrict__ bsf,
        const float* __restrict__ tv, const float* __restrict__ rw,
        unsigned int* __restrict__ Tab) {
    int bi = blockIdx.x, tid = threadIdx.x;
    long i = ((long)bi * 256 + tid) * 8;
    {
        f32x4 a = *(const f32x4*)&X[i];
        f32x4 b = *(const f32x4*)&X[i + 4];
        u32x4 r;
        r.x = (unsigned)f2bf(a[0]) | ((unsigned)f2bf(a[1]) << 16);
        r.y = (unsigned)f2bf(a[2]) | ((unsigned)f2bf(a[3]) << 16);
        r.z = (unsigned)f2bf(b[0]) | ((unsigned)f2bf(b[1]) << 16);
        r.w = (unsigned)f2bf(b[2]) | ((unsigned)f2bf(b[3]) << 16);
        *(u32x4*)&Xb[i] = r;
    }
    if (bi < 12) {
        int ib = bi * 256 + tid;
        bsf[ib] = (ib < 2048) ? bq[ib] : ((ib < 2560) ? bk[ib - 2048] : bv[ib - 2560]);
    }
    if (bi < 1024) {
        int m = bi * 4 + (tid >> 6);
        int fi = tid & 63;
        float t = tv[m];
        float f = t * powf(10000.f, -(float)fi / 64.f) * rw[fi];
        Tab[m * 64 + fi] = (unsigned)f2bf(cosf(f)) | ((unsigned)f2bf(sinf(f)) << 16);
    }
}

// ---------------------------------------------------------------------------
// GEMM1 + bias + RoPE fused.  A=Xb bf16 [4096][2048], Bt=Wt bf16 [3072][2048].
// Grid (24,32): bx 0..15 -> Q head bx; 16..19 -> K head bx-16; 20..23 -> V.
// R10: BK=64 (2 MFMA k-steps per barrier bracket).  LDS slot c holds logical
// oct (c&7)^(row&7); frag read at (s*4+quad)^(l16&7) -> 2-way max (free).
// Q heads pre-scaled by scale*log2e.
// ---------------------------------------------------------------------------
__global__ __launch_bounds__(256) void gemm_qkv_rope(
        const unsigned short* __restrict__ A,
        const unsigned short* __restrict__ Bt,
        const float* __restrict__ bsf,
        const unsigned int* __restrict__ Tab,
        unsigned short* __restrict__ Qr,
        unsigned short* __restrict__ Kr,
        unsigned short* __restrict__ Vt) {
    __shared__ __align__(16) char smem[32768];           // As 16K | Bs 16K
    unsigned short* As = (unsigned short*)smem;
    unsigned short* Bs = (unsigned short*)(smem + 16384);
    float* Ep = (float*)smem;                            // epilogue 32x132 fp32

    const int tid = threadIdx.x;
    const int wid = tid >> 6, lane = tid & 63, quad = lane >> 4, l16 = lane & 15;
    const int wr = wid >> 1, wc = wid & 1;
    const int m0 = blockIdx.y * 128, n0 = blockIdx.x * 128;
    const int bx = blockIdx.x;
    const int l7 = l16 & 7;

    f32x4 acc[4][4];
    #pragma unroll
    for (int i = 0; i < 4; i++)
        #pragma unroll
        for (int j = 0; j < 4; j++)
            #pragma unroll
            for (int c = 0; c < 4; c++) acc[i][j][c] = 0.f;

    for (int k0 = 0; k0 < 2048; k0 += 64) {
        #pragma unroll
        for (int i = 0; i < 4; i++) {
            int c = tid + 256 * i;
            int row = c >> 3, loct = ((c & 7) ^ (row & 7)) * 8;
            gload_lds16(&A[(long)(m0 + row) * 2048 + k0 + loct], &As[c * 8]);
        }
        #pragma unroll
        for (int i = 0; i < 4; i++) {
            int c = tid + 256 * i;
            int row = c >> 3, loct = ((c & 7) ^ (row & 7)) * 8;
            gload_lds16(&Bt[(long)(n0 + row) * 2048 + k0 + loct], &Bs[c * 8]);
        }
        __syncthreads();
        #pragma unroll
        for (int s = 0; s < 2; s++) {
            bf16x8 af[4], bfr[4];
            #pragma unroll
            for (int mi = 0; mi < 4; mi++)
                af[mi] = *(const bf16x8*)
                    &As[(wr * 64 + mi * 16 + l16) * 64 + (((s * 4 + quad) ^ l7)) * 8];
            #pragma unroll
            for (int ni = 0; ni < 4; ni++)
                bfr[ni] = *(const bf16x8*)
                    &Bs[(wc * 64 + ni * 16 + l16) * 64 + (((s * 4 + quad) ^ l7)) * 8];
            #pragma unroll
            for (int mi = 0; mi < 4; mi++)
                #pragma unroll
                for (int ni = 0; ni < 4; ni++)
                    acc[mi][ni] = __builtin_amdgcn_mfma_f32_16x16x32_bf16(
                        af[mi], bfr[ni], acc[mi][ni], 0, 0, 0);
        }
        __syncthreads();
    }

    // ---- fused epilogue (unchanged from R9) ----
    float bv4[4];
    #pragma unroll
    for (int ni = 0; ni < 4; ni++) bv4[ni] = bsf[n0 + wc * 64 + ni * 16 + l16];
    const bool isV = (bx >= 20);
    const float qs = (bx < 16) ? (0.08838834764831845f * 1.4426950408889634f) : 1.0f;

    const int lr = tid >> 3, jj = tid & 7, j0 = jj * 8;

    u32x4 tq[4][2];
    if (!isV) {
        #pragma unroll
        for (int mi = 0; mi < 4; mi++) {
            int gm = m0 + ((lr >> 4) << 6) + mi * 16 + (lr & 15);
            tq[mi][0] = *(const u32x4*)&Tab[(long)gm * 64 + j0];
            tq[mi][1] = *(const u32x4*)&Tab[(long)gm * 64 + j0 + 4];
        }
    }

    #pragma unroll
    for (int mi = 0; mi < 4; mi++) {
        #pragma unroll
        for (int ni = 0; ni < 4; ni++)
            #pragma unroll
            for (int r = 0; r < 4; r++)
                Ep[(wr * 16 + quad * 4 + r) * 132 + wc * 64 + ni * 16 + l16] =
                    acc[mi][ni][r] + bv4[ni];
        __syncthreads();
        if (!isV) {
            const int gm = m0 + ((lr >> 4) << 6) + mi * 16 + (lr & 15);
            const int bb = gm >> 11, s = gm & 2047;
            unsigned short* dst = (bx < 16)
                ? Qr + ((long)(bb * NH + bx) * S_LEN + s) * HD
                : Kr + ((long)(bb * NKV + (bx - 16)) * S_LEN + s) * HD;
            f32x4 x1a = *(f32x4*)&Ep[lr * 132 + j0];
            f32x4 x1b = *(f32x4*)&Ep[lr * 132 + j0 + 4];
            f32x4 x2a = *(f32x4*)&Ep[lr * 132 + 64 + j0];
            f32x4 x2b = *(f32x4*)&Ep[lr * 132 + 64 + j0 + 4];
            f32x4 la, lb, ha, hb;
            #pragma unroll
            for (int e = 0; e < 4; e++) {
                float ca = __builtin_bit_cast(float, tq[mi][0][e] << 16);
                float sa = __builtin_bit_cast(float, tq[mi][0][e] & 0xffff0000u);
                float cb = __builtin_bit_cast(float, tq[mi][1][e] << 16);
                float sb = __builtin_bit_cast(float, tq[mi][1][e] & 0xffff0000u);
                la[e] = (x1a[e] * ca - x2a[e] * sa) * qs;
                ha[e] = (x2a[e] * ca + x1a[e] * sa) * qs;
                lb[e] = (x1b[e] * cb - x2b[e] * sb) * qs;
                hb[e] = (x2b[e] * cb + x1b[e] * sb) * qs;
            }
            u32x4 lo, hi;
            lo.x = (unsigned)f2bf(la[0]) | ((unsigned)f2bf(la[1]) << 16);
            lo.y = (unsigned)f2bf(la[2]) | ((unsigned)f2bf(la[3]) << 16);
            lo.z = (unsigned)f2bf(lb[0]) | ((unsigned)f2bf(lb[1]) << 16);
            lo.w = (unsigned)f2bf(lb[2]) | ((unsigned)f2bf(lb[3]) << 16);
            hi.x = (unsigned)f2bf(ha[0]) | ((unsigned)f2bf(ha[1]) << 16);
            hi.y = (unsigned)f2bf(ha[2]) | ((unsigned)f2bf(ha[3]) << 16);
            hi.z = (unsigned)f2bf(hb[0]) | ((unsigned)f2bf(hb[1]) << 16);
            hi.w = (unsigned)f2bf(hb[2]) | ((unsigned)f2bf(hb[3]) << 16);
            *(u32x4*)&dst[j0] = lo;
            *(u32x4*)&dst[64 + j0] = hi;
        } else {
            const int d = tid >> 1, sh = tid & 1;
            const int gmb = m0 + sh * 64 + mi * 16;
            const int bb = gmb >> 11, s0 = gmb & 2047;
            unsigned short* dst =
                Vt + ((long)(bb * NKV + (bx - 20)) * HD + d) * S_LEN + s0;
            unsigned short pv[16];
            #pragma unroll
            for (int t = 0; t < 16; t++)
                pv[t] = f2bf(Ep[(sh * 16 + t) * 132 + d]);
            u32x4 v0, v1;
            v0.x = (unsigned)pv[0]  | ((unsigned)pv[1]  << 16);
            v0.y = (unsigned)pv[2]  | ((unsigned)pv[3]  << 16);
            v0.z = (unsigned)pv[4]  | ((unsigned)pv[5]  << 16);
            v0.w = (unsigned)pv[6]  | ((unsigned)pv[7]  << 16);
            v1.x = (unsigned)pv[8]  | ((unsigned)pv[9]  << 16);
            v1.y = (unsigned)pv[10] | ((unsigned)pv[11] << 16);
            v1.z = (unsigned)pv[12] | ((unsigned)pv[13] << 16);
            v1.w = (unsigned)pv[14] | ((unsigned)pv[15] << 16);
            *(u32x4*)&dst[0] = v0;
            *(u32x4*)&dst[8] = v1;
        }
        __syncthreads();
    }
}

// ---------------------------------------------------------------------------
// GEMM2: d_out fp32 = AO bf16 x WoT^T.  BK=64 swizzled K-loop.
// ---------------------------------------------------------------------------
template <typename CT>
__global__ __launch_bounds__(256) void gemm_bt_async(
        const unsigned short* __restrict__ A,
        const unsigned short* __restrict__ Bt,
        CT* __restrict__ C,
        const float* __restrict__ bias,
        int K, int lda, int ldb, int ldc) {
    __shared__ __align__(16) unsigned short As[128 * 64];
    __shared__ __align__(16) unsigned short Bs[128 * 64];
    const int tid = threadIdx.x;
    const int wid = tid >> 6, lane = tid & 63, quad = lane >> 4, l16 = lane & 15;
    const int wr = wid >> 1, wc = wid & 1;
    const int m0 = blockIdx.y * 128, n0 = blockIdx.x * 128;
    const int l7 = l16 & 7;

    f32x4 acc[4][4];
    #pragma unroll
    for (int i = 0; i < 4; i++)
        #pragma unroll
        for (int j = 0; j < 4; j++)
            #pragma unroll
            for (int c = 0; c < 4; c++) acc[i][j][c] = 0.f;

    for (int k0 = 0; k0 < K; k0 += 64) {
        #pragma unroll
        for (int i = 0; i < 4; i++) {
            int c = tid + 256 * i;
            int row = c >> 3, loct = ((c & 7) ^ (row & 7)) * 8;
            gload_lds16(&A[(long)(m0 + row) * lda + k0 + loct], &As[c * 8]);
        }
        #pragma unroll
        for (int i = 0; i < 4; i++) {
            int c = tid + 256 * i;
            int row = c >> 3, loct = ((c & 7) ^ (row & 7)) * 8;
            gload_lds16(&Bt[(long)(n0 + row) * ldb + k0 + loct], &Bs[c * 8]);
        }
        __syncthreads();
        #pragma unroll
        for (int s = 0; s < 2; s++) {
            bf16x8 af[4], bfr[4];
            #pragma unroll
            for (int mi = 0; mi < 4; mi++)
                af[mi] = *(const bf16x8*)
                    &As[(wr * 64 + mi * 16 + l16) * 64 + (((s * 4 + quad) ^ l7)) * 8];
            #pragma unroll
            for (int ni = 0; ni < 4; ni++)
                bfr[ni] = *(const bf16x8*)
                    &Bs[(wc * 64 + ni * 16 + l16) * 64 + (((s * 4 + quad) ^ l7)) * 8];
            #pragma unroll
            for (int mi = 0; mi < 4; mi++)
                #pragma unroll
                for (int ni = 0; ni < 4; ni++)
                    acc[mi][ni] = __builtin_amdgcn_mfma_f32_16x16x32_bf16(
                        af[mi], bfr[ni], acc[mi][ni], 0, 0, 0);
        }
        __syncthreads();
    }

    #pragma unroll
    for (int mi = 0; mi < 4; mi++) {
        #pragma unroll
        for (int ni = 0; ni < 4; ni++) {
            int gn = n0 + wc * 64 + ni * 16 + l16;
            float bv_ = bias ? bias[gn] : 0.f;
            #pragma unroll
            for (int r = 0; r < 4; r++) {
                int gm = m0 + wr * 64 + mi * 16 + quad * 4 + r;
                float v = acc[mi][ni][r] + bv_;
                if constexpr (sizeof(CT) == 4) C[(long)gm * ldc + gn] = v;
                else                           C[(long)gm * ldc + gn] = f2bf(v);
            }
        }
    }
}

// ---------------------------------------------------------------------------
// Causal flash attention, GQA, transposed scores (R7/R9 structure).
// R10: wave-uniform rescale skip (__any); HW-packed bf16 converts.
// ---------------------------------------------------------------------------
__global__ __launch_bounds__(512, 4) void attn_kernel(
        const unsigned short* __restrict__ Qr,
        const unsigned short* __restrict__ Kr,
        const unsigned short* __restrict__ Vt,
        unsigned short* __restrict__ Out) {
    __shared__ __align__(16) unsigned short Ks[64 * 128];
    __shared__ __align__(16) unsigned short Vs[128 * 64];
    __shared__ __align__(16) unsigned short Ps[8][16 * 68];

    const int h = blockIdx.x, b = blockIdx.z;
    const int qt = b ? blockIdx.y : (int)(gridDim.y - 1 - blockIdx.y);
    const int tid = threadIdx.x, w = tid >> 6, lane = tid & 63;
    const int quad = lane >> 4, l16 = lane & 15;
    const int hk = h >> 2;
    const unsigned short* Qb = Qr + (long)((b * NH + h) * S_LEN) * HD;
    const unsigned short* Kb = Kr + (long)((b * NKV + hk) * S_LEN) * HD;
    const unsigned short* Vb = Vt + (long)((b * NKV + hk) * HD) * S_LEN;
    const int qw = qt * 128 + w * 16;
    const int q  = qw + l16;
    const float MASK_MIN = -3.0e38f;

    bf16x8 qf[4];
    #pragma unroll
    for (int kc = 0; kc < 4; kc++)
        qf[kc] = *(const bf16x8*)&Qb[(long)q * HD + kc * 32 + quad * 8];

    f32x4 o[8];
    #pragma unroll
    for (int db = 0; db < 8; db++)
        #pragma unroll
        for (int c = 0; c < 4; c++) o[db][c] = 0.f;
    float mr = MASK_MIN, lr = 0.f;

    const int sK0 = tid, sK1 = tid + 512;
    const int kR0 = sK0 >> 4, kC0 = ((sK0 & 15) ^ (kR0 & 15)) * 8;
    const int kR1 = sK1 >> 4, kC1 = ((sK1 & 15) ^ (kR1 & 15)) * 8;
    const int vR0 = sK0 >> 3, vC0 = ((sK0 & 7) ^ (vR0 & 7)) * 8;
    const int vR1 = sK1 >> 3, vC1 = ((sK1 & 7) ^ (vR1 & 7)) * 8;

    const int nkt = 2 * qt + 2;
    for (int kt = 0; kt < nkt; kt++) {
        const int k0 = kt * 64;
        __syncthreads();
        gload_lds16(&Kb[(long)(k0 + kR0) * HD + kC0], &Ks[sK0 * 8]);
        gload_lds16(&Kb[(long)(k0 + kR1) * HD + kC1], &Ks[sK1 * 8]);
        gload_lds16(&Vb[(long)vR0 * S_LEN + k0 + vC0], &Vs[sK0 * 8]);
        gload_lds16(&Vb[(long)vR1 * S_LEN + k0 + vC1], &Vs[sK1 * 8]);
        __syncthreads();

        if (k0 > qw + 15) continue;

        f32x4 sc[4];
        #pragma unroll
        for (int nb = 0; nb < 4; nb++) {
            #pragma unroll
            for (int c = 0; c < 4; c++) sc[nb][c] = 0.f;
            #pragma unroll
            for (int kc = 0; kc < 4; kc++) {
                bf16x8 kf = *(const bf16x8*)
                    &Ks[(nb * 16 + l16) * 128 + (((kc * 4 + quad) ^ l16) * 8)];
                sc[nb] = __builtin_amdgcn_mfma_f32_16x16x32_bf16(kf, qf[kc], sc[nb], 0, 0, 0);
            }
        }
        if (k0 + 63 > qw) {   // diagonal tile: mask only (Q pre-scaled)
            #pragma unroll
            for (int nb = 0; nb < 4; nb++) {
                int kvb = k0 + nb * 16 + quad * 4;
                #pragma unroll
                for (int r = 0; r < 4; r++)
                    sc[nb][r] = (kvb + r > q) ? MASK_MIN : sc[nb][r];
            }
        }
        float tm = MASK_MIN;
        #pragma unroll
        for (int nb = 0; nb < 4; nb++)
            #pragma unroll
            for (int r = 0; r < 4; r++) tm = fmaxf(tm, sc[nb][r]);
        tm = fmaxf(tm, __shfl_xor(tm, 16));
        tm = fmaxf(tm, __shfl_xor(tm, 32));

        float mn = mr;
        if (__any(tm > mr)) {               // wave-uniform: rescale needed
            mn = fmaxf(mr, tm);
            float alpha = exp2f(mr - mn);
            mr = mn;
            lr *= alpha;
            #pragma unroll
            for (int db = 0; db < 8; db++)
                #pragma unroll
                for (int c = 0; c < 4; c++) o[db][c] *= alpha;
        }
        float rs = 0.f;
        #pragma unroll
        for (int nb = 0; nb < 4; nb++) {
            float pv0 = exp2f(sc[nb][0] - mn), pv1 = exp2f(sc[nb][1] - mn);
            float pv2 = exp2f(sc[nb][2] - mn), pv3 = exp2f(sc[nb][3] - mn);
            rs += (pv0 + pv1) + (pv2 + pv3);
            bf16x4 pk4 = { (__bf16)pv0, (__bf16)pv1, (__bf16)pv2, (__bf16)pv3 };
            *(bf16x4*)&Ps[w][l16 * 68 + nb * 16 + quad * 4] = pk4;
        }
        rs += __shfl_xor(rs, 16);
        rs += __shfl_xor(rs, 32);
        lr += rs;

        #pragma unroll
        for (int kk = 0; kk < 2; kk++) {
            bf16x8 pf = *(const bf16x8*)&Ps[w][l16 * 68 + kk * 32 + quad * 8];
            #pragma unroll
            for (int db = 0; db < 8; db++) {
                bf16x8 vf = *(const bf16x8*)
                    &Vs[(db * 16 + l16) * 64 + (((kk * 4 + quad) ^ (l16 & 7)) * 8)];
                o[db] = __builtin_amdgcn_mfma_f32_16x16x32_bf16(vf, pf, o[db], 0, 0, 0);
            }
        }
    }

    float inv_l = 1.0f / lr;
    long obase = (long)(b * S_LEN + q) * 2048 + h * 128 + quad * 4;
    #pragma unroll
    for (int db = 0; db < 8; db++) {
        bf16x4 pk4 = { (__bf16)(o[db][0] * inv_l), (__bf16)(o[db][1] * inv_l),
                       (__bf16)(o[db][2] * inv_l), (__bf16)(o[db][3] * inv_l) };
        *(bf16x4*)&Out[obase + db * 16] = pk4;
    }
}

// ---------------------------------------------------------------------------
extern "C" void kernel_launch(void* const* d_in, const int* in_sizes, int n_in,
                              void* d_out, int out_size, void* d_ws, size_t ws_size,
                              hipStream_t stream) {
    const float* X  = (const float*)d_in[0];
    const float* tv = (const float*)d_in[1];
    const float* wq = (const float*)d_in[2];
    const float* bq = (const float*)d_in[3];
    const float* wk = (const float*)d_in[4];
    const float* bk = (const float*)d_in[5];
    const float* wv = (const float*)d_in[6];
    const float* bv = (const float*)d_in[7];
    const float* wo = (const float*)d_in[8];
    const float* rw = (const float*)d_in[9];

    // Workspace (~56 MB):
    //   Wt 12.6MB ([wq|wk|wv]^T -> reused for wo^T after gemm1)
    //   bsf 12KB, Tab 1MB, Qr 16.8MB, Kr/Vt 8.4MB, AO 16.8MB (=Xb alias)
    char* ws = (char*)d_ws;
    unsigned short* Wt  = (unsigned short*)ws; ws += 3072L * 2048 * 2;
    float*          bsf = (float*)ws;          ws += 3072L * 4;
    unsigned int*   Tab = (unsigned int*)ws;   ws += 4096L * 64 * 4;
    unsigned short* Qr  = (unsigned short*)ws; ws += (long)BATCH * NH  * S_LEN * HD * 2;
    unsigned short* Kr  = (unsigned short*)ws; ws += (long)BATCH * NKV * S_LEN * HD * 2;
    unsigned short* Vt  = (unsigned short*)ws; ws += (long)BATCH * NKV * HD * S_LEN * 2;
    unsigned short* AO  = (unsigned short*)ws; ws += 4096L * 2048 * 2;
    unsigned short* Xb  = AO;   // alias: Xb dead (post-gemm1) before attn writes AO

    transpose_qkv<<<dim3(64, 64, 3), dim3(32, 8), 0, stream>>>(wq, wk, wv, Wt);
    prep_kernel<<<4096, 256, 0, stream>>>(X, Xb, bq, bk, bv, bsf, tv, rw, Tab);
    gemm_qkv_rope<<<dim3(24, 32), 256, 0, stream>>>(Xb, Wt, bsf, Tab, Qr, Kr, Vt);
    transpose_to_bf16<<<dim3(64, 64), dim3(32, 8), 0, stream>>>(wo, Wt, 2048, 2048, 0L, 2048);
    attn_kernel<<<dim3(NH, S_LEN / 128, BATCH), 512, 0, stream>>>(Qr, Kr, Vt, AO);
    gemm_bt_async<float><<<dim3(16, 32), 256, 0, stream>>>(
        AO, Wt, (float*)d_out, nullptr, 2048, 2048, 2048, 2048);
}